// Round 18
// baseline (121.474 us; speedup 1.0000x reference)
//
#include <hip/hip_runtime.h>
#include <hip/hip_bf16.h>
#include <stdint.h>

#define NFRM 8
#define NPTS 4096
#define NBOX 128
#define NS   32
#define TT   4
#define BB   2
#define FEATC 99
#define OUT1OFF (BB*NBOX*TT*NS*5)   /* 163840 */

/* ---- workspace layout (bytes) ---- */
#define WS_SPK    0u
#define WS_EPK    524288u
#define WS_FEATS  786432u
#define WS_SIDX   13762560u
#define WS_FLAGS  13893632u
#define WS_NCNT   14024704u
#define WS_NLST   14024736u
#define WS_VPK    14155808u
#define WS_VEK    14680096u
#define WS_VORIG  14942240u
#define WS_VCNT   15073312u
#define WS_WT     15073344u
/* wT00[5][16]@0  wT01[16][16]@80  wT02[16][32]@336  wT10[5][32]@848
   wT11[32][32]@1008  wT12[32][64]@2032  total 4080 floats */

/* -- K1: validity + packed arrays; block128 = weight transpose + zeroing -- */
__global__ void k_prep(const float* __restrict__ pts, const float* __restrict__ rois,
                       float4* __restrict__ spk, float2* __restrict__ epk,
                       const float* __restrict__ w00,const float* __restrict__ w01,
                       const float* __restrict__ w02,const float* __restrict__ w10,
                       const float* __restrict__ w11,const float* __restrict__ w12,
                       float* __restrict__ wt, int* __restrict__ flags,
                       int* __restrict__ gcnt)
{
    if (blockIdx.x == 128){
        int t = threadIdx.x;
        if (t == 0) *gcnt = 0;
        for (int idx=t; idx<80;   idx+=256){ int o=idx/5,  i=idx%5;  wt[      i*16+o]=w00[idx]; }
        for (int idx=t; idx<256;  idx+=256){ int o=idx/16, i=idx%16; wt[  80+ i*16+o]=w01[idx]; }
        for (int idx=t; idx<512;  idx+=256){ int o=idx/16, i=idx%16; wt[ 336+ i*32+o]=w02[idx]; }
        for (int idx=t; idx<160;  idx+=256){ int o=idx/5,  i=idx%5;  wt[ 848+ i*32+o]=w10[idx]; }
        for (int idx=t; idx<1024; idx+=256){ int o=idx/32, i=idx%32; wt[1008+ i*32+o]=w11[idx]; }
        for (int idx=t; idx<2048; idx+=256){ int o=idx/32, i=idx%32; wt[2032+ i*64+o]=w12[idx]; }
        return;
    }
    int f = blockIdx.x >> 4;
    int n = ((blockIdx.x & 15) << 8) | threadIdx.x;
    __shared__ float bqx[NBOX], bqy[NBOX], brv[NBOX];
    if (threadIdx.x < NBOX){
        const float* bp = rois + (size_t)(f*NBOX + threadIdx.x)*7;
        float bx=bp[0], by=bp[1], dx=bp[3], dy=bp[4];
        float hx=__fmul_rn(dx,0.5f), hy=__fmul_rn(dy,0.5f);
        float hd=sqrtf(__fadd_rn(__fmul_rn(hx,hx),__fmul_rn(hy,hy)));
        brv[threadIdx.x]=ceilf(__fdiv_rn(__fmul_rn(hd,1.1f),0.4f));
        bqx[threadIdx.x]=floorf(__fdiv_rn(__fsub_rn(bx,-75.2f),0.4f));
        bqy[threadIdx.x]=floorf(__fdiv_rn(__fsub_rn(by,-75.2f),0.4f));
    }
    flags[f*NPTS+n] = 0;
    __syncthreads();
    const float* pp = pts + (size_t)(f*NPTS+n)*5;
    float x=pp[0], y=pp[1], z=pp[2], it=pp[3], ts=pp[4];
    float cx=floorf(__fdiv_rn(__fsub_rn(x,-75.2f),0.4f));
    float cy=floorf(__fdiv_rn(__fsub_rn(y,-75.2f),0.4f));
    float v=0.f;
    for (int m=0;m<NBOX;m++)
        if (fabsf(bqx[m]-cx)<brv[m] && fabsf(bqy[m]-cy)<brv[m]){ v=1.f; break; }
    spk[f*NPTS+n]=make_float4(x,y,z,v);
    epk[f*NPTS+n]=make_float2(it,ts);
}

/* ---------------- K1b: order-preserving compaction of valid points ------ */
__global__ __launch_bounds__(1024) void k_valid(
    const float4* __restrict__ spk, const float2* __restrict__ epk,
    float4* __restrict__ vpk, float2* __restrict__ vek,
    int* __restrict__ vorig, int* __restrict__ vcnt)
{
    int f = blockIdx.x;
    int tid = threadIdx.x, wv = tid >> 6, lane = tid & 63;
    __shared__ int wcnt[16];
    __shared__ int sbase;
    if (tid == 0) sbase = 0;
    __syncthreads();
    uint64_t below = (1ull<<lane)-1ull;
    for (int j0=0; j0<NPTS; j0+=1024){
        int j = j0 + tid;
        float4 q = spk[f*NPTS+j];
        float2 e = epk[f*NPTS+j];
        bool pred = q.w > 0.5f;
        uint64_t m = __ballot(pred);
        int lp = __popcll(m & below);
        if (lane == 0) wcnt[wv] = __popcll(m);
        __syncthreads();
        int off = sbase;
        for (int w=0; w<wv; w++) off += wcnt[w];
        if (pred){
            int pos = off + lp;
            float sb = __fadd_rn(__fadd_rn(__fmul_rn(q.x,q.x),__fmul_rn(q.y,q.y)),__fmul_rn(q.z,q.z));
            vpk[f*NPTS+pos] = make_float4(q.x,q.y,q.z,sb);
            vek[f*NPTS+pos] = e;
            vorig[f*NPTS+pos] = j;
        }
        __syncthreads();
        if (tid == 0){ int t=0; for (int w=0;w<16;w++) t+=wcnt[w]; sbase += t; }
        __syncthreads();
    }
    if (tid == 0) vcnt[f] = sbase;
}

/* ------ K2: per-box stable top-k -> out0, sidx; fused dedupe-append ----- */
__global__ void k_select(const float4* __restrict__ spk, const float2* __restrict__ epk,
                         const float4* __restrict__ vpk, const int* __restrict__ vorig,
                         const int* __restrict__ vcnt,
                         const float* __restrict__ rois, float* __restrict__ out,
                         int* __restrict__ sidx, int* __restrict__ flags,
                         int* __restrict__ gcnt, int* __restrict__ glist)
{
    int id = blockIdx.x;           /* 0..1023 : (f, m) */
    int f = id >> 7, m = id & 127;
    int lane = threadIdx.x;
    const float* bp = rois + (size_t)(f*NBOX+m)*7;
    float bx=bp[0], by=bp[1], dx=bp[3], dy=bp[4];
    float hx=__fmul_rn(dx,0.5f), hy=__fmul_rn(dy,0.5f);
    float hd=sqrtf(__fadd_rn(__fmul_rn(hx,hx),__fmul_rn(hy,hy)));
    float rr=__fmul_rn(hd,1.1f);

    __shared__ int lt[32], lf[32];
    const float4* fsp = spk + f*NPTS;
    const float4* fvp = vpk + f*NPTS;
    const int*    fvo = vorig + f*NPTS;
    int vc = vcnt[f];
    uint64_t below = (1ull<<lane)-1ull;

    /* phase A: masked candidates from valid list, 2-deep pipelined */
    int cT=0;
    for (int v0=0; v0<vc; v0+=128){
        int viA = v0 + lane;
        int viB = v0 + 64 + lane;
        int vicA = min(viA, vc-1);
        int vicB = min(viB, vc-1);
        float4 qA = fvp[vicA];
        float4 qB = fvp[vicB];
        {
            float ddx=__fsub_rn(bx,qA.x), ddy=__fsub_rn(by,qA.y);
            float dis=sqrtf(__fadd_rn(__fmul_rn(ddx,ddx),__fmul_rn(ddy,ddy)));
            bool pm = (viA < vc) && (dis <= rr);
            uint64_t mT=__ballot(pm);
            if (pm){ int pos=cT+__popcll(mT&below); if (pos<32) lt[pos]=fvo[vicA]; }
            cT += __popcll(mT);
            if (cT>=32) break;
        }
        if (v0 + 64 < vc){
            float ddx=__fsub_rn(bx,qB.x), ddy=__fsub_rn(by,qB.y);
            float dis=sqrtf(__fadd_rn(__fmul_rn(ddx,ddx),__fmul_rn(ddy,ddy)));
            bool pm = (viB < vc) && (dis <= rr);
            uint64_t mT=__ballot(pm);
            if (pm){ int pos=cT+__popcll(mT&below); if (pos<32) lt[pos]=fvo[vicB]; }
            cT += __popcll(mT);
            if (cT>=32) break;
        }
    }
    /* phase B: fillers = first 32 original indices failing the mask */
    int cF=0;
    for (int j0=0; j0<NPTS; j0+=64){
        int j=j0+lane;
        float4 q = fsp[j];
        float ddx=__fsub_rn(bx,q.x), ddy=__fsub_rn(by,q.y);
        float dis=sqrtf(__fadd_rn(__fmul_rn(ddx,ddx),__fmul_rn(ddy,ddy)));
        bool fl = !((dis <= rr) && (q.w > 0.5f));
        uint64_t mF=__ballot(fl);
        if (fl){ int pos=cF+__popcll(mF&below); if (pos<32) lf[pos]=j; }
        cF += __popcll(mF);
        if (cF>=32) break;
    }
    __syncthreads();
    cT = min(cT,32);
    if (lane < 32){
        int s = lane;
        bool masked = s < cT;
        int idx = masked ? lt[s] : lf[s-cT];
        float mk = masked ? 1.f : 0.f;
        sidx[(f*NBOX+m)*NS+s]=idx;
        int b = f >> 2, t = f & 3;
        size_t row = (((size_t)(b*NBOX+m))*TT + t)*NS + s;
        float4 q = fsp[idx]; float2 e = epk[f*NPTS+idx];
        float* o0 = out + row*5;
        o0[0]=q.x*mk; o0[1]=q.y*mk; o0[2]=q.z*mk; o0[3]=e.x*mk; o0[4]=e.y*mk;
        /* fused dedupe-append to global needlist */
        int old = atomicExch(&flags[f*NPTS+idx], 1);
        bool fresh = (old == 0);
        uint64_t mm = __ballot(fresh);
        if (fresh){
            int ldr = __ffsll((unsigned long long)mm) - 1;
            int base = 0;
            if (lane == ldr) base = atomicAdd(gcnt, __popcll(mm));
            base = __shfl(base, ldr);
            glist[base + __popcll(mm & below)] = (f<<12) | idx;
        }
    }
}

/* -- K4: block-per-point; wave0 scan -> shared lists; 4-wave MLP split;
      coalesced wT loads; LDS float4 h-broadcast ------------------------- */
__global__ __launch_bounds__(256) void k_mlp(
    const float4* __restrict__ spk, const float2* __restrict__ epk,
    const float4* __restrict__ vpk, const float2* __restrict__ vek,
    const int* __restrict__ vcnt,
    const int* __restrict__ gcntp, const int* __restrict__ glist,
    float* __restrict__ feats, const float* __restrict__ wt,
    const float* __restrict__ b00,const float* __restrict__ b01,
    const float* __restrict__ b02,const float* __restrict__ b10,
    const float* __restrict__ b11,const float* __restrict__ b12)
{
    int gcnt = *gcntp;
    if ((int)blockIdx.x >= gcnt) return;
    int tid = threadIdx.x;
    int wv = tid >> 6, lane = tid & 63;
    __shared__ int slst[48];            /* [0..15]=r1 list, [16..47]=r2 list */
    __shared__ int scn[2];
    __shared__ float h1buf[4][4][36];
    __shared__ float h2buf[4][4][36];
    __shared__ float p0[3][32];
    __shared__ float p1[3][64];
    int* l1 = slst;
    int* l2 = slst+16;
    float (*h1b)[36] = h1buf[wv];
    float (*h2b)[36] = h2buf[wv];

    /* ---- per-lane weight rows, loaded COALESCED from transposed copy ---- */
    float wr00[5], wr01[16], wr02[16], wr10[5], wr11[32], wr12[32];
    float br00=0.f, br01=0.f, br02=0.f, br10=0.f, br11=0.f, br12=0.f;
    #pragma unroll
    for (int i=0;i<5;i++){ wr00[i]=0.f; wr10[i]=0.f; }
    #pragma unroll
    for (int i=0;i<16;i++){ wr01[i]=0.f; wr02[i]=0.f; }
    #pragma unroll
    for (int i=0;i<32;i++){ wr11[i]=0.f; wr12[i]=0.f; }
    if (lane < 16){
        #pragma unroll
        for (int i=0;i<5;i++)  wr00[i]=wt[i*16+lane];
        br00=b00[lane];
        #pragma unroll
        for (int i=0;i<16;i++) wr01[i]=wt[80+i*16+lane];
        br01=b01[lane];
    }
    if (lane < 32){
        #pragma unroll
        for (int i=0;i<16;i++) wr02[i]=wt[336+i*32+lane];
        br02=b02[lane];
        #pragma unroll
        for (int i=0;i<5;i++)  wr10[i]=wt[848+i*32+lane];
        br10=b10[lane];
        #pragma unroll
        for (int i=0;i<32;i++) wr11[i]=wt[1008+i*32+lane];
        br11=b11[lane];
    }
    #pragma unroll
    for (int i=0;i<32;i++) wr12[i]=wt[2032+i*64+lane];
    br12=b12[lane];

    const float RR1 = (float)(0.8*0.8);
    const float RR2 = (float)(1.6*1.6);
    uint64_t below = (1ull<<lane)-1ull;

    for (int li = blockIdx.x; li < gcnt; li += gridDim.x){
        int pe = glist[li];
        int f = pe >> 12, n = pe & 4095;
        const float4* fsp = spk + f*NPTS;
        const float2* fep = epk + f*NPTS;
        const float4* fvp = vpk + f*NPTS;
        const float2* fve = vek + f*NPTS;
        int vc = vcnt[f];
        float4 me = fsp[n];
        float sa = __fadd_rn(__fadd_rn(__fmul_rn(me.x,me.x),__fmul_rn(me.y,me.y)),__fmul_rn(me.z,me.z));

        /* ---- neighbor scan: wave 0 only, 2-deep pipelined loads ---- */
        if (wv == 0){
            int cnt1=0, cnt2=0;
            for (int v0=0; v0<vc; v0+=128){
                int viA = v0 + lane;
                int viB = v0 + 64 + lane;
                int vicA = min(viA, vc-1);
                int vicB = min(viB, vc-1);
                float4 qA = fvp[vicA];
                float4 qB = fvp[vicB];
                {
                    float dot = __fadd_rn(__fadd_rn(__fmul_rn(me.x,qA.x),__fmul_rn(me.y,qA.y)),__fmul_rn(me.z,qA.z));
                    float d2 = fmaxf(__fsub_rn(__fadd_rn(sa,qA.w),__fmul_rn(2.0f,dot)), 0.f);
                    bool inb = (viA < vc);
                    bool p1b = inb && (d2 < RR1);
                    bool p2b = inb && (d2 < RR2);
                    uint64_t m1 = __ballot(p1b), m2 = __ballot(p2b);
                    if (p1b){ int pos = cnt1 + __popcll(m1 & below); if (pos < 16) l1[pos] = viA; }
                    if (p2b){ int pos = cnt2 + __popcll(m2 & below); if (pos < 32) l2[pos] = viA; }
                    cnt1 += __popcll(m1); cnt2 += __popcll(m2);
                    if (cnt1 >= 16 && cnt2 >= 32) break;
                }
                if (v0 + 64 < vc){
                    float dot = __fadd_rn(__fadd_rn(__fmul_rn(me.x,qB.x),__fmul_rn(me.y,qB.y)),__fmul_rn(me.z,qB.z));
                    float d2 = fmaxf(__fsub_rn(__fadd_rn(sa,qB.w),__fmul_rn(2.0f,dot)), 0.f);
                    bool inb = (viB < vc);
                    bool p1b = inb && (d2 < RR1);
                    bool p2b = inb && (d2 < RR2);
                    uint64_t m1 = __ballot(p1b), m2 = __ballot(p2b);
                    if (p1b){ int pos = cnt1 + __popcll(m1 & below); if (pos < 16) l1[pos] = viB; }
                    if (p2b){ int pos = cnt2 + __popcll(m2 & below); if (pos < 32) l2[pos] = viB; }
                    cnt1 += __popcll(m1); cnt2 += __popcll(m2);
                    if (cnt1 >= 16 && cnt2 >= 32) break;
                }
            }
            if (lane == 0){ scn[0] = min(cnt1,16); scn[1] = min(cnt2,32); }
        }
        __syncthreads();
        int cnt1 = scn[0], cnt2 = scn[1];

        float* fo = feats + (size_t)(f*NPTS+n)*FEATC;
        float4 q0 = fsp[0]; float2 e0 = fep[0];

        /* ---- MLP0: wave handles kk = wv + 4j (j=0..3), LDS h-bcast ---- */
        float pm0;
        {
            float4 qb[4]; float2 eb[4];
            #pragma unroll
            for (int j=0;j<4;j++){
                int kk = wv + 4*j;
                int vi = (cnt1>0) ? ((kk<cnt1)? l1[kk] : l1[0]) : -1;
                if (vi >= 0){ qb[j]=fvp[vi]; eb[j]=fve[vi]; }
                else        { qb[j]=q0;      eb[j]=e0; }
            }
            #pragma unroll
            for (int j=0;j<4;j++){
                float a1 = br00;
                a1 += __fsub_rn(qb[j].x,me.x)*wr00[0];
                a1 += __fsub_rn(qb[j].y,me.y)*wr00[1];
                a1 += __fsub_rn(qb[j].z,me.z)*wr00[2];
                a1 += eb[j].x*wr00[3];
                a1 += eb[j].y*wr00[4];
                float h = fmaxf(a1,0.f);
                if (lane < 16) h1b[j][lane] = h;
            }
            float a2[4] = {br01,br01,br01,br01};
            #pragma unroll
            for (int c4=0;c4<4;c4++){
                float4 hv[4];
                #pragma unroll
                for (int j=0;j<4;j++) hv[j] = *(const float4*)&h1b[j][c4*4];
                #pragma unroll
                for (int cc=0;cc<4;cc++){
                    float w = wr01[c4*4+cc];
                    #pragma unroll
                    for (int j=0;j<4;j++){
                        float h = (cc==0)?hv[j].x:(cc==1)?hv[j].y:(cc==2)?hv[j].z:hv[j].w;
                        a2[j] += h*w;
                    }
                }
            }
            #pragma unroll
            for (int j=0;j<4;j++){
                float h = fmaxf(a2[j],0.f);
                if (lane < 16) h2b[j][lane] = h;
            }
            float a3[4] = {br02,br02,br02,br02};
            #pragma unroll
            for (int c4=0;c4<4;c4++){
                float4 hv[4];
                #pragma unroll
                for (int j=0;j<4;j++) hv[j] = *(const float4*)&h2b[j][c4*4];
                #pragma unroll
                for (int cc=0;cc<4;cc++){
                    float w = wr02[c4*4+cc];
                    #pragma unroll
                    for (int j=0;j<4;j++){
                        float h = (cc==0)?hv[j].x:(cc==1)?hv[j].y:(cc==2)?hv[j].z:hv[j].w;
                        a3[j] += h*w;
                    }
                }
            }
            pm0 = fmaxf(fmaxf(fmaxf(a3[0],0.f), fmaxf(a3[1],0.f)),
                        fmaxf(fmaxf(a3[2],0.f), fmaxf(a3[3],0.f)));
        }

        /* ---- MLP1: wave handles kk = wv + 4(jb+j), jb in {0,4} ---- */
        float pm1 = 0.f;
        #pragma unroll 1
        for (int jb=0; jb<8; jb+=4){
            float4 qb[4]; float2 eb[4];
            #pragma unroll
            for (int j=0;j<4;j++){
                int kk = wv + 4*(jb+j);
                int vi = (cnt2>0) ? ((kk<cnt2)? l2[kk] : l2[0]) : -1;
                if (vi >= 0){ qb[j]=fvp[vi]; eb[j]=fve[vi]; }
                else        { qb[j]=q0;      eb[j]=e0; }
            }
            #pragma unroll
            for (int j=0;j<4;j++){
                float a1 = br10;
                a1 += __fsub_rn(qb[j].x,me.x)*wr10[0];
                a1 += __fsub_rn(qb[j].y,me.y)*wr10[1];
                a1 += __fsub_rn(qb[j].z,me.z)*wr10[2];
                a1 += eb[j].x*wr10[3];
                a1 += eb[j].y*wr10[4];
                float h = fmaxf(a1,0.f);
                if (lane < 32) h1b[j][lane] = h;
            }
            float a2[4] = {br11,br11,br11,br11};
            #pragma unroll
            for (int c4=0;c4<8;c4++){
                float4 hv[4];
                #pragma unroll
                for (int j=0;j<4;j++) hv[j] = *(const float4*)&h1b[j][c4*4];
                #pragma unroll
                for (int cc=0;cc<4;cc++){
                    float w = wr11[c4*4+cc];
                    #pragma unroll
                    for (int j=0;j<4;j++){
                        float h = (cc==0)?hv[j].x:(cc==1)?hv[j].y:(cc==2)?hv[j].z:hv[j].w;
                        a2[j] += h*w;
                    }
                }
            }
            #pragma unroll
            for (int j=0;j<4;j++){
                float h = fmaxf(a2[j],0.f);
                if (lane < 32) h2b[j][lane] = h;
            }
            float a3[4] = {br12,br12,br12,br12};
            #pragma unroll
            for (int c4=0;c4<8;c4++){
                float4 hv[4];
                #pragma unroll
                for (int j=0;j<4;j++) hv[j] = *(const float4*)&h2b[j][c4*4];
                #pragma unroll
                for (int cc=0;cc<4;cc++){
                    float w = wr12[c4*4+cc];
                    #pragma unroll
                    for (int j=0;j<4;j++){
                        float h = (cc==0)?hv[j].x:(cc==1)?hv[j].y:(cc==2)?hv[j].z:hv[j].w;
                        a3[j] += h*w;
                    }
                }
            }
            #pragma unroll
            for (int j=0;j<4;j++) pm1 = fmaxf(pm1, fmaxf(a3[j],0.f));
        }

        /* ---- cross-wave max reduce (exact) ---- */
        if (wv > 0){
            if (lane < 32) p0[wv-1][lane] = pm0;
            p1[wv-1][lane] = pm1;
        }
        __syncthreads();
        if (wv == 0){
            float r0 = fmaxf(fmaxf(pm0, p0[0][lane & 31]),
                             fmaxf(p0[1][lane & 31], p0[2][lane & 31]));
            float r1 = fmaxf(fmaxf(pm1, p1[0][lane]),
                             fmaxf(p1[1][lane], p1[2][lane]));
            if (lane < 3){
                float mv = (lane==0)? me.x : ((lane==1)? me.y : me.z);
                fo[lane] = mv;
            }
            if (lane < 32) fo[3+lane] = r0;
            fo[35+lane] = r1;
        }
        __syncthreads();
    }
}

/* ---------------- K5: gather feats rows -> out1 ------------------------- */
__global__ void k_gather(const float* __restrict__ feats, const int* __restrict__ sidx,
                         float* __restrict__ out)
{
    int id = blockIdx.x;           /* 0..1023 : (f, m) */
    int f = id >> 7, m = id & 127;
    int tid = threadIdx.x;
    int s = tid >> 3, j = tid & 7;
    int idx = sidx[(f*NBOX+m)*NS+s];
    int b = f >> 2, t = f & 3;
    size_t row = (((size_t)(b*NBOX+m))*TT + t)*NS + s;
    const float* fi = feats + (size_t)(f*NPTS+idx)*FEATC;
    float* o1 = out + OUT1OFF + row*FEATC;
    for (int c=j; c<FEATC; c+=8) o1[c]=fi[c];
}

extern "C" void kernel_launch(void* const* d_in, const int* in_sizes, int n_in,
                              void* d_out, int out_size, void* d_ws, size_t ws_size,
                              hipStream_t stream)
{
    const float* pts  = (const float*)d_in[0];
    const float* rois = (const float*)d_in[1];
    const float* w00=(const float*)d_in[2],  *b00=(const float*)d_in[3];
    const float* w01=(const float*)d_in[4],  *b01=(const float*)d_in[5];
    const float* w02=(const float*)d_in[6],  *b02=(const float*)d_in[7];
    const float* w10=(const float*)d_in[8],  *b10=(const float*)d_in[9];
    const float* w11=(const float*)d_in[10], *b11=(const float*)d_in[11];
    const float* w12=(const float*)d_in[12], *b12=(const float*)d_in[13];
    float* out = (float*)d_out;

    char* ws = (char*)d_ws;
    float4* spk   = (float4*)(ws + WS_SPK);
    float2* epk   = (float2*)(ws + WS_EPK);
    float*  feats = (float*) (ws + WS_FEATS);
    int*    sidx  = (int*)   (ws + WS_SIDX);
    int*    flags = (int*)   (ws + WS_FLAGS);
    int*    gcnt  = (int*)   (ws + WS_NCNT);
    int*    glist = (int*)   (ws + WS_NLST);
    float4* vpk   = (float4*)(ws + WS_VPK);
    float2* vek   = (float2*)(ws + WS_VEK);
    int*    vorig = (int*)   (ws + WS_VORIG);
    int*    vcnt  = (int*)   (ws + WS_VCNT);
    float*  wtr   = (float*) (ws + WS_WT);

    hipLaunchKernelGGL(k_prep,   dim3(NFRM*16+1), dim3(256), 0, stream,
                       pts, rois, spk, epk, w00,w01,w02,w10,w11,w12, wtr, flags, gcnt);
    hipLaunchKernelGGL(k_valid,  dim3(NFRM), dim3(1024), 0, stream, spk, epk, vpk, vek, vorig, vcnt);
    hipLaunchKernelGGL(k_select, dim3(NFRM*NBOX), dim3(64), 0, stream,
                       spk, epk, vpk, vorig, vcnt, rois, out, sidx, flags, gcnt, glist);
    hipLaunchKernelGGL(k_mlp,    dim3(6144), dim3(256), 0, stream,
                       spk, epk, vpk, vek, vcnt, gcnt, glist, feats, wtr,
                       b00,b01,b02,b10,b11,b12);
    hipLaunchKernelGGL(k_gather, dim3(NFRM*NBOX), dim3(256), 0, stream,
                       feats, sidx, out);
}

// Round 19
// 120.409 us; speedup vs baseline: 1.0088x; 1.0088x over previous
//
#include <hip/hip_runtime.h>
#include <hip/hip_bf16.h>
#include <stdint.h>

#define NFRM 8
#define NPTS 4096
#define NBOX 128
#define NS   32
#define TT   4
#define BB   2
#define FEATC 99
#define OUT1OFF (BB*NBOX*TT*NS*5)   /* 163840 */

/* ---- workspace layout (bytes) ---- */
#define WS_SPK    0u
#define WS_EPK    524288u
#define WS_FEATS  786432u
#define WS_SIDX   13762560u
#define WS_FLAGS  13893632u
#define WS_NCNT   14024704u
#define WS_NLST   14024736u
#define WS_VPK    14155808u
#define WS_VEK    14680096u
#define WS_VORIG  14942240u
#define WS_VCNT   15073312u
#define WS_WT     15073344u
/* wT00[5][16]@0  wT01[16][16]@80  wT02[16][32]@336  wT10[5][32]@848
   wT11[32][32]@1008  wT12[32][64]@2032  total 4080 floats */

/* -- K1: validity + packed arrays; block128 = weight transpose + zeroing -- */
__global__ void k_prep(const float* __restrict__ pts, const float* __restrict__ rois,
                       float4* __restrict__ spk, float2* __restrict__ epk,
                       const float* __restrict__ w00,const float* __restrict__ w01,
                       const float* __restrict__ w02,const float* __restrict__ w10,
                       const float* __restrict__ w11,const float* __restrict__ w12,
                       float* __restrict__ wt, int* __restrict__ flags,
                       int* __restrict__ gcnt)
{
    if (blockIdx.x == 128){
        int t = threadIdx.x;
        if (t == 0) *gcnt = 0;
        for (int idx=t; idx<80;   idx+=256){ int o=idx/5,  i=idx%5;  wt[      i*16+o]=w00[idx]; }
        for (int idx=t; idx<256;  idx+=256){ int o=idx/16, i=idx%16; wt[  80+ i*16+o]=w01[idx]; }
        for (int idx=t; idx<512;  idx+=256){ int o=idx/16, i=idx%16; wt[ 336+ i*32+o]=w02[idx]; }
        for (int idx=t; idx<160;  idx+=256){ int o=idx/5,  i=idx%5;  wt[ 848+ i*32+o]=w10[idx]; }
        for (int idx=t; idx<1024; idx+=256){ int o=idx/32, i=idx%32; wt[1008+ i*32+o]=w11[idx]; }
        for (int idx=t; idx<2048; idx+=256){ int o=idx/32, i=idx%32; wt[2032+ i*64+o]=w12[idx]; }
        return;
    }
    int f = blockIdx.x >> 4;
    int n = ((blockIdx.x & 15) << 8) | threadIdx.x;
    __shared__ float bqx[NBOX], bqy[NBOX], brv[NBOX];
    if (threadIdx.x < NBOX){
        const float* bp = rois + (size_t)(f*NBOX + threadIdx.x)*7;
        float bx=bp[0], by=bp[1], dx=bp[3], dy=bp[4];
        float hx=__fmul_rn(dx,0.5f), hy=__fmul_rn(dy,0.5f);
        float hd=sqrtf(__fadd_rn(__fmul_rn(hx,hx),__fmul_rn(hy,hy)));
        brv[threadIdx.x]=ceilf(__fdiv_rn(__fmul_rn(hd,1.1f),0.4f));
        bqx[threadIdx.x]=floorf(__fdiv_rn(__fsub_rn(bx,-75.2f),0.4f));
        bqy[threadIdx.x]=floorf(__fdiv_rn(__fsub_rn(by,-75.2f),0.4f));
    }
    flags[f*NPTS+n] = 0;
    __syncthreads();
    const float* pp = pts + (size_t)(f*NPTS+n)*5;
    float x=pp[0], y=pp[1], z=pp[2], it=pp[3], ts=pp[4];
    float cx=floorf(__fdiv_rn(__fsub_rn(x,-75.2f),0.4f));
    float cy=floorf(__fdiv_rn(__fsub_rn(y,-75.2f),0.4f));
    float v=0.f;
    for (int m=0;m<NBOX;m++)
        if (fabsf(bqx[m]-cx)<brv[m] && fabsf(bqy[m]-cy)<brv[m]){ v=1.f; break; }
    spk[f*NPTS+n]=make_float4(x,y,z,v);
    epk[f*NPTS+n]=make_float2(it,ts);
}

/* ---------------- K1b: order-preserving compaction of valid points ------ */
__global__ __launch_bounds__(1024) void k_valid(
    const float4* __restrict__ spk, const float2* __restrict__ epk,
    float4* __restrict__ vpk, float2* __restrict__ vek,
    int* __restrict__ vorig, int* __restrict__ vcnt)
{
    int f = blockIdx.x;
    int tid = threadIdx.x, wv = tid >> 6, lane = tid & 63;
    __shared__ int wcnt[16];
    __shared__ int sbase;
    if (tid == 0) sbase = 0;
    __syncthreads();
    uint64_t below = (1ull<<lane)-1ull;
    for (int j0=0; j0<NPTS; j0+=1024){
        int j = j0 + tid;
        float4 q = spk[f*NPTS+j];
        float2 e = epk[f*NPTS+j];
        bool pred = q.w > 0.5f;
        uint64_t m = __ballot(pred);
        int lp = __popcll(m & below);
        if (lane == 0) wcnt[wv] = __popcll(m);
        __syncthreads();
        int off = sbase;
        for (int w=0; w<wv; w++) off += wcnt[w];
        if (pred){
            int pos = off + lp;
            float sb = __fadd_rn(__fadd_rn(__fmul_rn(q.x,q.x),__fmul_rn(q.y,q.y)),__fmul_rn(q.z,q.z));
            vpk[f*NPTS+pos] = make_float4(q.x,q.y,q.z,sb);
            vek[f*NPTS+pos] = e;
            vorig[f*NPTS+pos] = j;
        }
        __syncthreads();
        if (tid == 0){ int t=0; for (int w=0;w<16;w++) t+=wcnt[w]; sbase += t; }
        __syncthreads();
    }
    if (tid == 0) vcnt[f] = sbase;
}

/* ------ K2: per-box stable top-k -> out0, sidx; fused dedupe-append ----- */
__global__ void k_select(const float4* __restrict__ spk, const float2* __restrict__ epk,
                         const float4* __restrict__ vpk, const int* __restrict__ vorig,
                         const int* __restrict__ vcnt,
                         const float* __restrict__ rois, float* __restrict__ out,
                         int* __restrict__ sidx, int* __restrict__ flags,
                         int* __restrict__ gcnt, int* __restrict__ glist)
{
    int id = blockIdx.x;           /* 0..1023 : (f, m) */
    int f = id >> 7, m = id & 127;
    int lane = threadIdx.x;
    const float* bp = rois + (size_t)(f*NBOX+m)*7;
    float bx=bp[0], by=bp[1], dx=bp[3], dy=bp[4];
    float hx=__fmul_rn(dx,0.5f), hy=__fmul_rn(dy,0.5f);
    float hd=sqrtf(__fadd_rn(__fmul_rn(hx,hx),__fmul_rn(hy,hy)));
    float rr=__fmul_rn(hd,1.1f);

    __shared__ int lt[32], lf[32];
    const float4* fsp = spk + f*NPTS;
    const float4* fvp = vpk + f*NPTS;
    const int*    fvo = vorig + f*NPTS;
    int vc = vcnt[f];
    uint64_t below = (1ull<<lane)-1ull;

    /* phase A: masked candidates from valid list, 2-deep pipelined */
    int cT=0;
    for (int v0=0; v0<vc; v0+=128){
        int viA = v0 + lane;
        int viB = v0 + 64 + lane;
        int vicA = min(viA, vc-1);
        int vicB = min(viB, vc-1);
        float4 qA = fvp[vicA];
        float4 qB = fvp[vicB];
        {
            float ddx=__fsub_rn(bx,qA.x), ddy=__fsub_rn(by,qA.y);
            float dis=sqrtf(__fadd_rn(__fmul_rn(ddx,ddx),__fmul_rn(ddy,ddy)));
            bool pm = (viA < vc) && (dis <= rr);
            uint64_t mT=__ballot(pm);
            if (pm){ int pos=cT+__popcll(mT&below); if (pos<32) lt[pos]=fvo[vicA]; }
            cT += __popcll(mT);
            if (cT>=32) break;
        }
        if (v0 + 64 < vc){
            float ddx=__fsub_rn(bx,qB.x), ddy=__fsub_rn(by,qB.y);
            float dis=sqrtf(__fadd_rn(__fmul_rn(ddx,ddx),__fmul_rn(ddy,ddy)));
            bool pm = (viB < vc) && (dis <= rr);
            uint64_t mT=__ballot(pm);
            if (pm){ int pos=cT+__popcll(mT&below); if (pos<32) lt[pos]=fvo[vicB]; }
            cT += __popcll(mT);
            if (cT>=32) break;
        }
    }
    /* phase B: fillers = first 32 original indices failing the mask */
    int cF=0;
    for (int j0=0; j0<NPTS; j0+=64){
        int j=j0+lane;
        float4 q = fsp[j];
        float ddx=__fsub_rn(bx,q.x), ddy=__fsub_rn(by,q.y);
        float dis=sqrtf(__fadd_rn(__fmul_rn(ddx,ddx),__fmul_rn(ddy,ddy)));
        bool fl = !((dis <= rr) && (q.w > 0.5f));
        uint64_t mF=__ballot(fl);
        if (fl){ int pos=cF+__popcll(mF&below); if (pos<32) lf[pos]=j; }
        cF += __popcll(mF);
        if (cF>=32) break;
    }
    __syncthreads();
    cT = min(cT,32);
    if (lane < 32){
        int s = lane;
        bool masked = s < cT;
        int idx = masked ? lt[s] : lf[s-cT];
        float mk = masked ? 1.f : 0.f;
        sidx[(f*NBOX+m)*NS+s]=idx;
        int b = f >> 2, t = f & 3;
        size_t row = (((size_t)(b*NBOX+m))*TT + t)*NS + s;
        float4 q = fsp[idx]; float2 e = epk[f*NPTS+idx];
        float* o0 = out + row*5;
        o0[0]=q.x*mk; o0[1]=q.y*mk; o0[2]=q.z*mk; o0[3]=e.x*mk; o0[4]=e.y*mk;
        /* fused dedupe-append to global needlist */
        int old = atomicExch(&flags[f*NPTS+idx], 1);
        bool fresh = (old == 0);
        uint64_t mm = __ballot(fresh);
        if (fresh){
            int ldr = __ffsll((unsigned long long)mm) - 1;
            int base = 0;
            if (lane == ldr) base = atomicAdd(gcnt, __popcll(mm));
            base = __shfl(base, ldr);
            glist[base + __popcll(mm & below)] = (f<<12) | idx;
        }
    }
}

/* -- K4: (point,half) wave-tasks; LDS h-bcast; atomicMax combine --------- */
__global__ __launch_bounds__(256) void k_mlp(
    const float4* __restrict__ spk, const float2* __restrict__ epk,
    const float4* __restrict__ vpk, const float2* __restrict__ vek,
    const int* __restrict__ vcnt,
    const int* __restrict__ gcntp, const int* __restrict__ glist,
    float* __restrict__ feats, const float* __restrict__ wt,
    const float* __restrict__ b00,const float* __restrict__ b01,
    const float* __restrict__ b02,const float* __restrict__ b10,
    const float* __restrict__ b11,const float* __restrict__ b12)
{
    int gcnt = *gcntp;
    int ntask = gcnt * 2;
    if ((int)blockIdx.x * 4 >= ntask) return;
    int tid = threadIdx.x;
    int wv = tid >> 6, lane = tid & 63;
    __shared__ int lists[4][48];
    __shared__ float h1buf[4][4][36];
    __shared__ float h2buf[4][4][36];
    int* l1 = lists[wv];
    int* l2 = lists[wv]+16;
    float (*h1b)[36] = h1buf[wv];
    float (*h2b)[36] = h2buf[wv];

    /* ---- per-lane weight rows, loaded COALESCED from transposed copy ---- */
    float wr00[5], wr01[16], wr02[16], wr10[5], wr11[32], wr12[32];
    float br00=0.f, br01=0.f, br02=0.f, br10=0.f, br11=0.f, br12=0.f;
    #pragma unroll
    for (int i=0;i<5;i++){ wr00[i]=0.f; wr10[i]=0.f; }
    #pragma unroll
    for (int i=0;i<16;i++){ wr01[i]=0.f; wr02[i]=0.f; }
    #pragma unroll
    for (int i=0;i<32;i++){ wr11[i]=0.f; wr12[i]=0.f; }
    if (lane < 16){
        #pragma unroll
        for (int i=0;i<5;i++)  wr00[i]=wt[i*16+lane];
        br00=b00[lane];
        #pragma unroll
        for (int i=0;i<16;i++) wr01[i]=wt[80+i*16+lane];
        br01=b01[lane];
    }
    if (lane < 32){
        #pragma unroll
        for (int i=0;i<16;i++) wr02[i]=wt[336+i*32+lane];
        br02=b02[lane];
        #pragma unroll
        for (int i=0;i<5;i++)  wr10[i]=wt[848+i*32+lane];
        br10=b10[lane];
        #pragma unroll
        for (int i=0;i<32;i++) wr11[i]=wt[1008+i*32+lane];
        br11=b11[lane];
    }
    #pragma unroll
    for (int i=0;i<32;i++) wr12[i]=wt[2032+i*64+lane];
    br12=b12[lane];

    const float RR1 = (float)(0.8*0.8);
    const float RR2 = (float)(1.6*1.6);
    uint64_t below = (1ull<<lane)-1ull;

    for (int ti = blockIdx.x*4 + wv; ti < ntask; ti += 16384){
        int li = ti >> 1, half = ti & 1;
        int pe = glist[li];
        int f = pe >> 12, n = pe & 4095;
        const float4* fsp = spk + f*NPTS;
        const float2* fep = epk + f*NPTS;
        const float4* fvp = vpk + f*NPTS;
        const float2* fve = vek + f*NPTS;
        int vc = vcnt[f];
        float4 me = fsp[n];
        float sa = __fadd_rn(__fadd_rn(__fmul_rn(me.x,me.x),__fmul_rn(me.y,me.y)),__fmul_rn(me.z,me.z));

        /* ---- neighbor scan over valid list ---- */
        int cnt1=0, cnt2=0;
        for (int v0=0; v0<vc; v0+=64){
            int vi = v0 + lane;
            int vic = min(vi, vc-1);
            float4 q = fvp[vic];
            float dot = __fadd_rn(__fadd_rn(__fmul_rn(me.x,q.x),__fmul_rn(me.y,q.y)),__fmul_rn(me.z,q.z));
            float d2 = fmaxf(__fsub_rn(__fadd_rn(sa,q.w),__fmul_rn(2.0f,dot)), 0.f);
            bool inb = (vi < vc);
            bool p1 = inb && (d2 < RR1);
            bool p2 = inb && (d2 < RR2);
            uint64_t m1 = __ballot(p1), m2 = __ballot(p2);
            if (p1){ int pos = cnt1 + __popcll(m1 & below); if (pos < 16) l1[pos] = vi; }
            if (p2){ int pos = cnt2 + __popcll(m2 & below); if (pos < 32) l2[pos] = vi; }
            cnt1 += __popcll(m1); cnt2 += __popcll(m2);
            if (cnt1 >= 16 && cnt2 >= 32) break;
        }
        cnt1 = min(cnt1,16); cnt2 = min(cnt2,32);

        float* fo = feats + (size_t)(f*NPTS+n)*FEATC;
        float4 q0 = fsp[0]; float2 e0 = fep[0];

        /* ---- MLP0: this half handles kb in {8h, 8h+4} ---- */
        {
            float pmax = 0.f;
            #pragma unroll 1
            for (int kq=0; kq<2; kq++){
                int kb = half*8 + kq*4;
                float4 qb[4]; float2 eb[4];
                #pragma unroll
                for (int j=0;j<4;j++){
                    int kk = kb+j;
                    int vi = (cnt1>0) ? ((kk<cnt1)? l1[kk] : l1[0]) : -1;
                    if (vi >= 0){ qb[j]=fvp[vi]; eb[j]=fve[vi]; }
                    else        { qb[j]=q0;      eb[j]=e0; }
                }
                #pragma unroll
                for (int j=0;j<4;j++){
                    float a1 = br00;
                    a1 += __fsub_rn(qb[j].x,me.x)*wr00[0];
                    a1 += __fsub_rn(qb[j].y,me.y)*wr00[1];
                    a1 += __fsub_rn(qb[j].z,me.z)*wr00[2];
                    a1 += eb[j].x*wr00[3];
                    a1 += eb[j].y*wr00[4];
                    float h = fmaxf(a1,0.f);
                    if (lane < 16) h1b[j][lane] = h;
                }
                float a2[4] = {br01,br01,br01,br01};
                #pragma unroll
                for (int c4=0;c4<4;c4++){
                    float4 hv[4];
                    #pragma unroll
                    for (int j=0;j<4;j++) hv[j] = *(const float4*)&h1b[j][c4*4];
                    #pragma unroll
                    for (int cc=0;cc<4;cc++){
                        float w = wr01[c4*4+cc];
                        #pragma unroll
                        for (int j=0;j<4;j++){
                            float h = (cc==0)?hv[j].x:(cc==1)?hv[j].y:(cc==2)?hv[j].z:hv[j].w;
                            a2[j] += h*w;
                        }
                    }
                }
                #pragma unroll
                for (int j=0;j<4;j++){
                    float h = fmaxf(a2[j],0.f);
                    if (lane < 16) h2b[j][lane] = h;
                }
                float a3[4] = {br02,br02,br02,br02};
                #pragma unroll
                for (int c4=0;c4<4;c4++){
                    float4 hv[4];
                    #pragma unroll
                    for (int j=0;j<4;j++) hv[j] = *(const float4*)&h2b[j][c4*4];
                    #pragma unroll
                    for (int cc=0;cc<4;cc++){
                        float w = wr02[c4*4+cc];
                        #pragma unroll
                        for (int j=0;j<4;j++){
                            float h = (cc==0)?hv[j].x:(cc==1)?hv[j].y:(cc==2)?hv[j].z:hv[j].w;
                            a3[j] += h*w;
                        }
                    }
                }
                #pragma unroll
                for (int j=0;j<4;j++) pmax = fmaxf(pmax, fmaxf(a3[j],0.f));
            }
            if (half==0 && lane < 3){
                float mv = (lane==0)? me.x : ((lane==1)? me.y : me.z);
                fo[lane] = mv;
            }
            if (lane < 32)
                atomicMax((unsigned int*)&fo[3+lane], __float_as_uint(pmax));
        }

        /* ---- MLP1: this half handles kb in {16h..16h+12} ---- */
        {
            float pmax = 0.f;
            #pragma unroll 1
            for (int kq=0; kq<4; kq++){
                int kb = half*16 + kq*4;
                float4 qb[4]; float2 eb[4];
                #pragma unroll
                for (int j=0;j<4;j++){
                    int kk = kb+j;
                    int vi = (cnt2>0) ? ((kk<cnt2)? l2[kk] : l2[0]) : -1;
                    if (vi >= 0){ qb[j]=fvp[vi]; eb[j]=fve[vi]; }
                    else        { qb[j]=q0;      eb[j]=e0; }
                }
                #pragma unroll
                for (int j=0;j<4;j++){
                    float a1 = br10;
                    a1 += __fsub_rn(qb[j].x,me.x)*wr10[0];
                    a1 += __fsub_rn(qb[j].y,me.y)*wr10[1];
                    a1 += __fsub_rn(qb[j].z,me.z)*wr10[2];
                    a1 += eb[j].x*wr10[3];
                    a1 += eb[j].y*wr10[4];
                    float h = fmaxf(a1,0.f);
                    if (lane < 32) h1b[j][lane] = h;
                }
                float a2[4] = {br11,br11,br11,br11};
                #pragma unroll
                for (int c4=0;c4<8;c4++){
                    float4 hv[4];
                    #pragma unroll
                    for (int j=0;j<4;j++) hv[j] = *(const float4*)&h1b[j][c4*4];
                    #pragma unroll
                    for (int cc=0;cc<4;cc++){
                        float w = wr11[c4*4+cc];
                        #pragma unroll
                        for (int j=0;j<4;j++){
                            float h = (cc==0)?hv[j].x:(cc==1)?hv[j].y:(cc==2)?hv[j].z:hv[j].w;
                            a2[j] += h*w;
                        }
                    }
                }
                #pragma unroll
                for (int j=0;j<4;j++){
                    float h = fmaxf(a2[j],0.f);
                    if (lane < 32) h2b[j][lane] = h;
                }
                float a3[4] = {br12,br12,br12,br12};
                #pragma unroll
                for (int c4=0;c4<8;c4++){
                    float4 hv[4];
                    #pragma unroll
                    for (int j=0;j<4;j++) hv[j] = *(const float4*)&h2b[j][c4*4];
                    #pragma unroll
                    for (int cc=0;cc<4;cc++){
                        float w = wr12[c4*4+cc];
                        #pragma unroll
                        for (int j=0;j<4;j++){
                            float h = (cc==0)?hv[j].x:(cc==1)?hv[j].y:(cc==2)?hv[j].z:hv[j].w;
                            a3[j] += h*w;
                        }
                    }
                }
                #pragma unroll
                for (int j=0;j<4;j++) pmax = fmaxf(pmax, fmaxf(a3[j],0.f));
            }
            atomicMax((unsigned int*)&fo[35+lane], __float_as_uint(pmax));
        }
    }
}

/* ---------------- K5: gather feats rows -> out1 ------------------------- */
__global__ void k_gather(const float* __restrict__ feats, const int* __restrict__ sidx,
                         float* __restrict__ out)
{
    int id = blockIdx.x;           /* 0..1023 : (f, m) */
    int f = id >> 7, m = id & 127;
    int tid = threadIdx.x;
    int s = tid >> 3, j = tid & 7;
    int idx = sidx[(f*NBOX+m)*NS+s];
    int b = f >> 2, t = f & 3;
    size_t row = (((size_t)(b*NBOX+m))*TT + t)*NS + s;
    const float* fi = feats + (size_t)(f*NPTS+idx)*FEATC;
    float* o1 = out + OUT1OFF + row*FEATC;
    for (int c=j; c<FEATC; c+=8) o1[c]=fi[c];
}

extern "C" void kernel_launch(void* const* d_in, const int* in_sizes, int n_in,
                              void* d_out, int out_size, void* d_ws, size_t ws_size,
                              hipStream_t stream)
{
    const float* pts  = (const float*)d_in[0];
    const float* rois = (const float*)d_in[1];
    const float* w00=(const float*)d_in[2],  *b00=(const float*)d_in[3];
    const float* w01=(const float*)d_in[4],  *b01=(const float*)d_in[5];
    const float* w02=(const float*)d_in[6],  *b02=(const float*)d_in[7];
    const float* w10=(const float*)d_in[8],  *b10=(const float*)d_in[9];
    const float* w11=(const float*)d_in[10], *b11=(const float*)d_in[11];
    const float* w12=(const float*)d_in[12], *b12=(const float*)d_in[13];
    float* out = (float*)d_out;

    char* ws = (char*)d_ws;
    float4* spk   = (float4*)(ws + WS_SPK);
    float2* epk   = (float2*)(ws + WS_EPK);
    float*  feats = (float*) (ws + WS_FEATS);
    int*    sidx  = (int*)   (ws + WS_SIDX);
    int*    flags = (int*)   (ws + WS_FLAGS);
    int*    gcnt  = (int*)   (ws + WS_NCNT);
    int*    glist = (int*)   (ws + WS_NLST);
    float4* vpk   = (float4*)(ws + WS_VPK);
    float2* vek   = (float2*)(ws + WS_VEK);
    int*    vorig = (int*)   (ws + WS_VORIG);
    int*    vcnt  = (int*)   (ws + WS_VCNT);
    float*  wtr   = (float*) (ws + WS_WT);

    /* zero feats region (atomicMax accumulators; outputs are >= 0) */
    hipMemsetAsync(ws + WS_FEATS, 0, WS_SIDX - WS_FEATS, stream);

    hipLaunchKernelGGL(k_prep,   dim3(NFRM*16+1), dim3(256), 0, stream,
                       pts, rois, spk, epk, w00,w01,w02,w10,w11,w12, wtr, flags, gcnt);
    hipLaunchKernelGGL(k_valid,  dim3(NFRM), dim3(1024), 0, stream, spk, epk, vpk, vek, vorig, vcnt);
    hipLaunchKernelGGL(k_select, dim3(NFRM*NBOX), dim3(64), 0, stream,
                       spk, epk, vpk, vorig, vcnt, rois, out, sidx, flags, gcnt, glist);
    hipLaunchKernelGGL(k_mlp,    dim3(4096), dim3(256), 0, stream,
                       spk, epk, vpk, vek, vcnt, gcnt, glist, feats, wtr,
                       b00,b01,b02,b10,b11,b12);
    hipLaunchKernelGGL(k_gather, dim3(NFRM*NBOX), dim3(256), 0, stream,
                       feats, sidx, out);
}

// Round 20
// 96.293 us; speedup vs baseline: 1.2615x; 1.2504x over previous
//
#include <hip/hip_runtime.h>
#include <hip/hip_bf16.h>
#include <stdint.h>

#define NFRM 8
#define NPTS 4096
#define NBOX 128
#define NS   32
#define TT   4
#define BB   2
#define FEATC 99
#define OUT1OFF (BB*NBOX*TT*NS*5)   /* 163840 */

/* ---- workspace layout (bytes) ---- */
#define WS_SPK    0u
#define WS_EPK    524288u
#define WS_FEATS  786432u
#define WS_SIDX   13762560u
#define WS_FLAGS  13893632u
#define WS_NCNT   14024704u
#define WS_NLST   14024736u
#define WS_VPK    14155808u
#define WS_VEK    14680096u
#define WS_VORIG  14942240u
#define WS_VCNT   15073312u
#define WS_WT     15073344u
#define WS_CCNT   15089728u   /* per-chunk valid counts: 8*16 ints */
/* wT00[5][16]@0  wT01[16][16]@80  wT02[16][32]@336  wT10[5][32]@848
   wT11[32][32]@1008  wT12[32][64]@2032  total 4080 floats */

/* -- K1: validity + packed arrays + per-chunk counts; block128 = wT ------ */
__global__ void k_prep(const float* __restrict__ pts, const float* __restrict__ rois,
                       float4* __restrict__ spk, float2* __restrict__ epk,
                       const float* __restrict__ w00,const float* __restrict__ w01,
                       const float* __restrict__ w02,const float* __restrict__ w10,
                       const float* __restrict__ w11,const float* __restrict__ w12,
                       float* __restrict__ wt, int* __restrict__ flags,
                       int* __restrict__ gcnt, int* __restrict__ ccnt)
{
    if (blockIdx.x == 128){
        int t = threadIdx.x;
        if (t == 0) *gcnt = 0;
        for (int idx=t; idx<80;   idx+=256){ int o=idx/5,  i=idx%5;  wt[      i*16+o]=w00[idx]; }
        for (int idx=t; idx<256;  idx+=256){ int o=idx/16, i=idx%16; wt[  80+ i*16+o]=w01[idx]; }
        for (int idx=t; idx<512;  idx+=256){ int o=idx/16, i=idx%16; wt[ 336+ i*32+o]=w02[idx]; }
        for (int idx=t; idx<160;  idx+=256){ int o=idx/5,  i=idx%5;  wt[ 848+ i*32+o]=w10[idx]; }
        for (int idx=t; idx<1024; idx+=256){ int o=idx/32, i=idx%32; wt[1008+ i*32+o]=w11[idx]; }
        for (int idx=t; idx<2048; idx+=256){ int o=idx/32, i=idx%32; wt[2032+ i*64+o]=w12[idx]; }
        return;
    }
    int f = blockIdx.x >> 4;
    int chunk = blockIdx.x & 15;
    int tid = threadIdx.x, wv = tid >> 6, lane = tid & 63;
    int n = (chunk << 8) | tid;
    __shared__ float bqx[NBOX], bqy[NBOX], brv[NBOX];
    __shared__ int wcnt[4];
    if (tid < NBOX){
        const float* bp = rois + (size_t)(f*NBOX + tid)*7;
        float bx=bp[0], by=bp[1], dx=bp[3], dy=bp[4];
        float hx=__fmul_rn(dx,0.5f), hy=__fmul_rn(dy,0.5f);
        float hd=sqrtf(__fadd_rn(__fmul_rn(hx,hx),__fmul_rn(hy,hy)));
        brv[tid]=ceilf(__fdiv_rn(__fmul_rn(hd,1.1f),0.4f));
        bqx[tid]=floorf(__fdiv_rn(__fsub_rn(bx,-75.2f),0.4f));
        bqy[tid]=floorf(__fdiv_rn(__fsub_rn(by,-75.2f),0.4f));
    }
    flags[f*NPTS+n] = 0;
    __syncthreads();
    const float* pp = pts + (size_t)(f*NPTS+n)*5;
    float x=pp[0], y=pp[1], z=pp[2], it=pp[3], ts=pp[4];
    float cx=floorf(__fdiv_rn(__fsub_rn(x,-75.2f),0.4f));
    float cy=floorf(__fdiv_rn(__fsub_rn(y,-75.2f),0.4f));
    bool pred=false;
    for (int m=0;m<NBOX;m++)
        if (fabsf(bqx[m]-cx)<brv[m] && fabsf(bqy[m]-cy)<brv[m]){ pred=true; break; }
    spk[f*NPTS+n]=make_float4(x,y,z,pred?1.f:0.f);
    epk[f*NPTS+n]=make_float2(it,ts);
    uint64_t m = __ballot(pred);
    if (lane == 0) wcnt[wv] = __popcll(m);
    __syncthreads();
    if (tid == 0) ccnt[f*16+chunk] = wcnt[0]+wcnt[1]+wcnt[2]+wcnt[3];
}

/* -- K1b: parallel order-preserving compaction (1 block per 256-chunk) --- */
__global__ void k_valid(const float4* __restrict__ spk, const float2* __restrict__ epk,
                        const int* __restrict__ ccnt,
                        float4* __restrict__ vpk, float2* __restrict__ vek,
                        int* __restrict__ vorig, int* __restrict__ vcnt)
{
    int f = blockIdx.x >> 4;
    int chunk = blockIdx.x & 15;
    int tid = threadIdx.x, wv = tid >> 6, lane = tid & 63;
    __shared__ int wcnt[4];
    int base = 0;
    for (int i=0;i<chunk;i++) base += ccnt[f*16+i];
    int j = (chunk << 8) | tid;
    float4 q = spk[f*NPTS+j];
    float2 e = epk[f*NPTS+j];
    bool pred = q.w > 0.5f;
    uint64_t m = __ballot(pred);
    uint64_t below = (1ull<<lane)-1ull;
    int lp = __popcll(m & below);
    if (lane == 0) wcnt[wv] = __popcll(m);
    __syncthreads();
    int off = base;
    for (int w=0; w<wv; w++) off += wcnt[w];
    if (pred){
        int pos = off + lp;
        float sb = __fadd_rn(__fadd_rn(__fmul_rn(q.x,q.x),__fmul_rn(q.y,q.y)),__fmul_rn(q.z,q.z));
        vpk[f*NPTS+pos] = make_float4(q.x,q.y,q.z,sb);
        vek[f*NPTS+pos] = e;
        vorig[f*NPTS+pos] = j;
    }
    if (chunk == 15 && tid == 0){
        int t = base + wcnt[0]+wcnt[1]+wcnt[2]+wcnt[3];
        vcnt[f] = t;
    }
}

/* ------ K2: per-box stable top-k -> out0, sidx; fused dedupe-append ----- */
__global__ void k_select(const float4* __restrict__ spk, const float2* __restrict__ epk,
                         const float4* __restrict__ vpk, const int* __restrict__ vorig,
                         const int* __restrict__ vcnt,
                         const float* __restrict__ rois, float* __restrict__ out,
                         int* __restrict__ sidx, int* __restrict__ flags,
                         int* __restrict__ gcnt, int* __restrict__ glist)
{
    int id = blockIdx.x;           /* 0..1023 : (f, m) */
    int f = id >> 7, m = id & 127;
    int lane = threadIdx.x;
    const float* bp = rois + (size_t)(f*NBOX+m)*7;
    float bx=bp[0], by=bp[1], dx=bp[3], dy=bp[4];
    float hx=__fmul_rn(dx,0.5f), hy=__fmul_rn(dy,0.5f);
    float hd=sqrtf(__fadd_rn(__fmul_rn(hx,hx),__fmul_rn(hy,hy)));
    float rr=__fmul_rn(hd,1.1f);

    __shared__ int lt[32], lf[32];
    const float4* fsp = spk + f*NPTS;
    const float4* fvp = vpk + f*NPTS;
    const int*    fvo = vorig + f*NPTS;
    int vc = vcnt[f];
    uint64_t below = (1ull<<lane)-1ull;

    /* phase A: masked candidates from valid list, 2-deep pipelined */
    int cT=0;
    for (int v0=0; v0<vc; v0+=128){
        int viA = v0 + lane;
        int viB = v0 + 64 + lane;
        int vicA = min(viA, vc-1);
        int vicB = min(viB, vc-1);
        float4 qA = fvp[vicA];
        float4 qB = fvp[vicB];
        {
            float ddx=__fsub_rn(bx,qA.x), ddy=__fsub_rn(by,qA.y);
            float dis=sqrtf(__fadd_rn(__fmul_rn(ddx,ddx),__fmul_rn(ddy,ddy)));
            bool pm = (viA < vc) && (dis <= rr);
            uint64_t mT=__ballot(pm);
            if (pm){ int pos=cT+__popcll(mT&below); if (pos<32) lt[pos]=fvo[vicA]; }
            cT += __popcll(mT);
            if (cT>=32) break;
        }
        if (v0 + 64 < vc){
            float ddx=__fsub_rn(bx,qB.x), ddy=__fsub_rn(by,qB.y);
            float dis=sqrtf(__fadd_rn(__fmul_rn(ddx,ddx),__fmul_rn(ddy,ddy)));
            bool pm = (viB < vc) && (dis <= rr);
            uint64_t mT=__ballot(pm);
            if (pm){ int pos=cT+__popcll(mT&below); if (pos<32) lt[pos]=fvo[vicB]; }
            cT += __popcll(mT);
            if (cT>=32) break;
        }
    }
    /* phase B: fillers = first 32 original indices failing the mask */
    int cF=0;
    for (int j0=0; j0<NPTS; j0+=64){
        int j=j0+lane;
        float4 q = fsp[j];
        float ddx=__fsub_rn(bx,q.x), ddy=__fsub_rn(by,q.y);
        float dis=sqrtf(__fadd_rn(__fmul_rn(ddx,ddx),__fmul_rn(ddy,ddy)));
        bool fl = !((dis <= rr) && (q.w > 0.5f));
        uint64_t mF=__ballot(fl);
        if (fl){ int pos=cF+__popcll(mF&below); if (pos<32) lf[pos]=j; }
        cF += __popcll(mF);
        if (cF>=32) break;
    }
    __syncthreads();
    cT = min(cT,32);
    if (lane < 32){
        int s = lane;
        bool masked = s < cT;
        int idx = masked ? lt[s] : lf[s-cT];
        float mk = masked ? 1.f : 0.f;
        sidx[(f*NBOX+m)*NS+s]=idx;
        int b = f >> 2, t = f & 3;
        size_t row = (((size_t)(b*NBOX+m))*TT + t)*NS + s;
        float4 q = fsp[idx]; float2 e = epk[f*NPTS+idx];
        float* o0 = out + row*5;
        o0[0]=q.x*mk; o0[1]=q.y*mk; o0[2]=q.z*mk; o0[3]=e.x*mk; o0[4]=e.y*mk;
        /* fused dedupe-append to global needlist */
        int old = atomicExch(&flags[f*NPTS+idx], 1);
        bool fresh = (old == 0);
        uint64_t mm = __ballot(fresh);
        if (fresh){
            int ldr = __ffsll((unsigned long long)mm) - 1;
            int base = 0;
            if (lane == ldr) base = atomicAdd(gcnt, __popcll(mm));
            base = __shfl(base, ldr);
            glist[base + __popcll(mm & below)] = (f<<12) | idx;
        }
    }
}

/* -- K4: scan + channel-major MLPs; h broadcast via LDS float4 (off-VALU) - */
__global__ __launch_bounds__(256) void k_mlp(
    const float4* __restrict__ spk, const float2* __restrict__ epk,
    const float4* __restrict__ vpk, const float2* __restrict__ vek,
    const int* __restrict__ vcnt,
    const int* __restrict__ gcntp, const int* __restrict__ glist,
    float* __restrict__ feats, const float* __restrict__ wt,
    const float* __restrict__ b00,const float* __restrict__ b01,
    const float* __restrict__ b02,const float* __restrict__ b10,
    const float* __restrict__ b11,const float* __restrict__ b12)
{
    int gcnt = *gcntp;
    if ((int)blockIdx.x * 4 >= gcnt) return;
    int tid = threadIdx.x;
    int wv = tid >> 6, lane = tid & 63;
    __shared__ int lists[4][48];
    __shared__ float h1buf[4][4][36];
    __shared__ float h2buf[4][4][36];
    int* l1 = lists[wv];
    int* l2 = lists[wv]+16;
    float (*h1b)[36] = h1buf[wv];
    float (*h2b)[36] = h2buf[wv];

    /* ---- per-lane weight rows, loaded COALESCED from transposed copy ---- */
    float wr00[5], wr01[16], wr02[16], wr10[5], wr11[32], wr12[32];
    float br00=0.f, br01=0.f, br02=0.f, br10=0.f, br11=0.f, br12=0.f;
    #pragma unroll
    for (int i=0;i<5;i++){ wr00[i]=0.f; wr10[i]=0.f; }
    #pragma unroll
    for (int i=0;i<16;i++){ wr01[i]=0.f; wr02[i]=0.f; }
    #pragma unroll
    for (int i=0;i<32;i++){ wr11[i]=0.f; wr12[i]=0.f; }
    if (lane < 16){
        #pragma unroll
        for (int i=0;i<5;i++)  wr00[i]=wt[i*16+lane];
        br00=b00[lane];
        #pragma unroll
        for (int i=0;i<16;i++) wr01[i]=wt[80+i*16+lane];
        br01=b01[lane];
    }
    if (lane < 32){
        #pragma unroll
        for (int i=0;i<16;i++) wr02[i]=wt[336+i*32+lane];
        br02=b02[lane];
        #pragma unroll
        for (int i=0;i<5;i++)  wr10[i]=wt[848+i*32+lane];
        br10=b10[lane];
        #pragma unroll
        for (int i=0;i<32;i++) wr11[i]=wt[1008+i*32+lane];
        br11=b11[lane];
    }
    #pragma unroll
    for (int i=0;i<32;i++) wr12[i]=wt[2032+i*64+lane];
    br12=b12[lane];

    const float RR1 = (float)(0.8*0.8);
    const float RR2 = (float)(1.6*1.6);
    uint64_t below = (1ull<<lane)-1ull;

    for (int li = blockIdx.x*4 + wv; li < gcnt; li += 8192){
        int pe = glist[li];
        int f = pe >> 12, n = pe & 4095;
        const float4* fsp = spk + f*NPTS;
        const float2* fep = epk + f*NPTS;
        const float4* fvp = vpk + f*NPTS;
        const float2* fve = vek + f*NPTS;
        int vc = vcnt[f];
        float4 me = fsp[n];
        float sa = __fadd_rn(__fadd_rn(__fmul_rn(me.x,me.x),__fmul_rn(me.y,me.y)),__fmul_rn(me.z,me.z));

        /* ---- neighbor scan over valid list ---- */
        int cnt1=0, cnt2=0;
        for (int v0=0; v0<vc; v0+=64){
            int vi = v0 + lane;
            int vic = min(vi, vc-1);
            float4 q = fvp[vic];
            float dot = __fadd_rn(__fadd_rn(__fmul_rn(me.x,q.x),__fmul_rn(me.y,q.y)),__fmul_rn(me.z,q.z));
            float d2 = fmaxf(__fsub_rn(__fadd_rn(sa,q.w),__fmul_rn(2.0f,dot)), 0.f);
            bool inb = (vi < vc);
            bool p1 = inb && (d2 < RR1);
            bool p2 = inb && (d2 < RR2);
            uint64_t m1 = __ballot(p1), m2 = __ballot(p2);
            if (p1){ int pos = cnt1 + __popcll(m1 & below); if (pos < 16) l1[pos] = vi; }
            if (p2){ int pos = cnt2 + __popcll(m2 & below); if (pos < 32) l2[pos] = vi; }
            cnt1 += __popcll(m1); cnt2 += __popcll(m2);
            if (cnt1 >= 16 && cnt2 >= 32) break;
        }
        cnt1 = min(cnt1,16); cnt2 = min(cnt2,32);

        float* fo = feats + (size_t)(f*NPTS+n)*FEATC;
        float4 q0 = fsp[0]; float2 e0 = fep[0];

        /* ---- MLP0: 16 nbrs, 5->16->16->32, batches of 4, LDS h-bcast ---- */
        {
            float pmax = 0.f;
            #pragma unroll 1
            for (int kb=0; kb<16; kb+=4){
                float4 qb[4]; float2 eb[4];
                #pragma unroll
                for (int j=0;j<4;j++){
                    int kk = kb+j;
                    int vi = (cnt1>0) ? ((kk<cnt1)? l1[kk] : l1[0]) : -1;
                    if (vi >= 0){ qb[j]=fvp[vi]; eb[j]=fve[vi]; }
                    else        { qb[j]=q0;      eb[j]=e0; }
                }
                #pragma unroll
                for (int j=0;j<4;j++){
                    float a1 = br00;
                    a1 += __fsub_rn(qb[j].x,me.x)*wr00[0];
                    a1 += __fsub_rn(qb[j].y,me.y)*wr00[1];
                    a1 += __fsub_rn(qb[j].z,me.z)*wr00[2];
                    a1 += eb[j].x*wr00[3];
                    a1 += eb[j].y*wr00[4];
                    float h = fmaxf(a1,0.f);
                    if (lane < 16) h1b[j][lane] = h;
                }
                float a2[4] = {br01,br01,br01,br01};
                #pragma unroll
                for (int c4=0;c4<4;c4++){
                    float4 hv[4];
                    #pragma unroll
                    for (int j=0;j<4;j++) hv[j] = *(const float4*)&h1b[j][c4*4];
                    #pragma unroll
                    for (int cc=0;cc<4;cc++){
                        float w = wr01[c4*4+cc];
                        #pragma unroll
                        for (int j=0;j<4;j++){
                            float h = (cc==0)?hv[j].x:(cc==1)?hv[j].y:(cc==2)?hv[j].z:hv[j].w;
                            a2[j] += h*w;
                        }
                    }
                }
                #pragma unroll
                for (int j=0;j<4;j++){
                    float h = fmaxf(a2[j],0.f);
                    if (lane < 16) h2b[j][lane] = h;
                }
                float a3[4] = {br02,br02,br02,br02};
                #pragma unroll
                for (int c4=0;c4<4;c4++){
                    float4 hv[4];
                    #pragma unroll
                    for (int j=0;j<4;j++) hv[j] = *(const float4*)&h2b[j][c4*4];
                    #pragma unroll
                    for (int cc=0;cc<4;cc++){
                        float w = wr02[c4*4+cc];
                        #pragma unroll
                        for (int j=0;j<4;j++){
                            float h = (cc==0)?hv[j].x:(cc==1)?hv[j].y:(cc==2)?hv[j].z:hv[j].w;
                            a3[j] += h*w;
                        }
                    }
                }
                #pragma unroll
                for (int j=0;j<4;j++) pmax = fmaxf(pmax, fmaxf(a3[j],0.f));
            }
            if (lane < 3){
                float mv = (lane==0)? me.x : ((lane==1)? me.y : me.z);
                fo[lane] = mv;
            }
            if (lane < 32) fo[3+lane] = pmax;
        }

        /* ---- MLP1: 32 nbrs, 5->32->32->64, batches of 4, LDS h-bcast ---- */
        {
            float pmax = 0.f;
            #pragma unroll 1
            for (int kb=0; kb<32; kb+=4){
                float4 qb[4]; float2 eb[4];
                #pragma unroll
                for (int j=0;j<4;j++){
                    int kk = kb+j;
                    int vi = (cnt2>0) ? ((kk<cnt2)? l2[kk] : l2[0]) : -1;
                    if (vi >= 0){ qb[j]=fvp[vi]; eb[j]=fve[vi]; }
                    else        { qb[j]=q0;      eb[j]=e0; }
                }
                #pragma unroll
                for (int j=0;j<4;j++){
                    float a1 = br10;
                    a1 += __fsub_rn(qb[j].x,me.x)*wr10[0];
                    a1 += __fsub_rn(qb[j].y,me.y)*wr10[1];
                    a1 += __fsub_rn(qb[j].z,me.z)*wr10[2];
                    a1 += eb[j].x*wr10[3];
                    a1 += eb[j].y*wr10[4];
                    float h = fmaxf(a1,0.f);
                    if (lane < 32) h1b[j][lane] = h;
                }
                float a2[4] = {br11,br11,br11,br11};
                #pragma unroll
                for (int c4=0;c4<8;c4++){
                    float4 hv[4];
                    #pragma unroll
                    for (int j=0;j<4;j++) hv[j] = *(const float4*)&h1b[j][c4*4];
                    #pragma unroll
                    for (int cc=0;cc<4;cc++){
                        float w = wr11[c4*4+cc];
                        #pragma unroll
                        for (int j=0;j<4;j++){
                            float h = (cc==0)?hv[j].x:(cc==1)?hv[j].y:(cc==2)?hv[j].z:hv[j].w;
                            a2[j] += h*w;
                        }
                    }
                }
                #pragma unroll
                for (int j=0;j<4;j++){
                    float h = fmaxf(a2[j],0.f);
                    if (lane < 32) h2b[j][lane] = h;
                }
                float a3[4] = {br12,br12,br12,br12};
                #pragma unroll
                for (int c4=0;c4<8;c4++){
                    float4 hv[4];
                    #pragma unroll
                    for (int j=0;j<4;j++) hv[j] = *(const float4*)&h2b[j][c4*4];
                    #pragma unroll
                    for (int cc=0;cc<4;cc++){
                        float w = wr12[c4*4+cc];
                        #pragma unroll
                        for (int j=0;j<4;j++){
                            float h = (cc==0)?hv[j].x:(cc==1)?hv[j].y:(cc==2)?hv[j].z:hv[j].w;
                            a3[j] += h*w;
                        }
                    }
                }
                #pragma unroll
                for (int j=0;j<4;j++) pmax = fmaxf(pmax, fmaxf(a3[j],0.f));
            }
            fo[35+lane] = pmax;
        }
    }
}

/* ---------------- K5: gather feats rows -> out1 ------------------------- */
__global__ void k_gather(const float* __restrict__ feats, const int* __restrict__ sidx,
                         float* __restrict__ out)
{
    int id = blockIdx.x;           /* 0..1023 : (f, m) */
    int f = id >> 7, m = id & 127;
    int tid = threadIdx.x;
    int s = tid >> 3, j = tid & 7;
    int idx = sidx[(f*NBOX+m)*NS+s];
    int b = f >> 2, t = f & 3;
    size_t row = (((size_t)(b*NBOX+m))*TT + t)*NS + s;
    const float* fi = feats + (size_t)(f*NPTS+idx)*FEATC;
    float* o1 = out + OUT1OFF + row*FEATC;
    for (int c=j; c<FEATC; c+=8) o1[c]=fi[c];
}

extern "C" void kernel_launch(void* const* d_in, const int* in_sizes, int n_in,
                              void* d_out, int out_size, void* d_ws, size_t ws_size,
                              hipStream_t stream)
{
    const float* pts  = (const float*)d_in[0];
    const float* rois = (const float*)d_in[1];
    const float* w00=(const float*)d_in[2],  *b00=(const float*)d_in[3];
    const float* w01=(const float*)d_in[4],  *b01=(const float*)d_in[5];
    const float* w02=(const float*)d_in[6],  *b02=(const float*)d_in[7];
    const float* w10=(const float*)d_in[8],  *b10=(const float*)d_in[9];
    const float* w11=(const float*)d_in[10], *b11=(const float*)d_in[11];
    const float* w12=(const float*)d_in[12], *b12=(const float*)d_in[13];
    float* out = (float*)d_out;

    char* ws = (char*)d_ws;
    float4* spk   = (float4*)(ws + WS_SPK);
    float2* epk   = (float2*)(ws + WS_EPK);
    float*  feats = (float*) (ws + WS_FEATS);
    int*    sidx  = (int*)   (ws + WS_SIDX);
    int*    flags = (int*)   (ws + WS_FLAGS);
    int*    gcnt  = (int*)   (ws + WS_NCNT);
    int*    glist = (int*)   (ws + WS_NLST);
    float4* vpk   = (float4*)(ws + WS_VPK);
    float2* vek   = (float2*)(ws + WS_VEK);
    int*    vorig = (int*)   (ws + WS_VORIG);
    int*    vcnt  = (int*)   (ws + WS_VCNT);
    float*  wtr   = (float*) (ws + WS_WT);
    int*    ccnt  = (int*)   (ws + WS_CCNT);

    hipLaunchKernelGGL(k_prep,   dim3(NFRM*16+1), dim3(256), 0, stream,
                       pts, rois, spk, epk, w00,w01,w02,w10,w11,w12, wtr, flags, gcnt, ccnt);
    hipLaunchKernelGGL(k_valid,  dim3(NFRM*16), dim3(256), 0, stream,
                       spk, epk, ccnt, vpk, vek, vorig, vcnt);
    hipLaunchKernelGGL(k_select, dim3(NFRM*NBOX), dim3(64), 0, stream,
                       spk, epk, vpk, vorig, vcnt, rois, out, sidx, flags, gcnt, glist);
    hipLaunchKernelGGL(k_mlp,    dim3(2048), dim3(256), 0, stream,
                       spk, epk, vpk, vek, vcnt, gcnt, glist, feats, wtr,
                       b00,b01,b02,b10,b11,b12);
    hipLaunchKernelGGL(k_gather, dim3(NFRM*NBOX), dim3(256), 0, stream,
                       feats, sidx, out);
}

// Round 21
// 95.262 us; speedup vs baseline: 1.2752x; 1.0108x over previous
//
#include <hip/hip_runtime.h>
#include <hip/hip_bf16.h>
#include <stdint.h>

#define NFRM 8
#define NPTS 4096
#define NBOX 128
#define NS   32
#define TT   4
#define BB   2
#define FEATC 99
#define OUT1OFF (BB*NBOX*TT*NS*5)   /* 163840 */

/* ---- workspace layout (bytes) ---- */
#define WS_SPK    0u
#define WS_EPK    524288u
#define WS_FEATS  786432u
#define WS_SIDX   13762560u
#define WS_FLAGS  13893632u
#define WS_NCNT   14024704u
#define WS_NLST   14024736u
#define WS_VPK    14155808u
#define WS_VEK    14680096u
#define WS_VORIG  14942240u
#define WS_VCNT   15073312u
#define WS_WT     15073344u
#define WS_CCNT   15089728u   /* per-chunk valid counts: 8*16 ints */

/* -- K1: validity + packed arrays + per-chunk counts; block128 = wT ------ */
__global__ void k_prep(const float* __restrict__ pts, const float* __restrict__ rois,
                       float4* __restrict__ spk, float2* __restrict__ epk,
                       const float* __restrict__ w00,const float* __restrict__ w01,
                       const float* __restrict__ w02,const float* __restrict__ w10,
                       const float* __restrict__ w11,const float* __restrict__ w12,
                       float* __restrict__ wt, int* __restrict__ flags,
                       int* __restrict__ gcnt, int* __restrict__ ccnt)
{
    if (blockIdx.x == 128){
        int t = threadIdx.x;
        if (t == 0) *gcnt = 0;
        for (int idx=t; idx<80;   idx+=256){ int o=idx/5,  i=idx%5;  wt[      i*16+o]=w00[idx]; }
        for (int idx=t; idx<256;  idx+=256){ int o=idx/16, i=idx%16; wt[  80+ i*16+o]=w01[idx]; }
        for (int idx=t; idx<512;  idx+=256){ int o=idx/16, i=idx%16; wt[ 336+ i*32+o]=w02[idx]; }
        for (int idx=t; idx<160;  idx+=256){ int o=idx/5,  i=idx%5;  wt[ 848+ i*32+o]=w10[idx]; }
        for (int idx=t; idx<1024; idx+=256){ int o=idx/32, i=idx%32; wt[1008+ i*32+o]=w11[idx]; }
        for (int idx=t; idx<2048; idx+=256){ int o=idx/32, i=idx%32; wt[2032+ i*64+o]=w12[idx]; }
        return;
    }
    int f = blockIdx.x >> 4;
    int chunk = blockIdx.x & 15;
    int tid = threadIdx.x, wv = tid >> 6, lane = tid & 63;
    int n = (chunk << 8) | tid;
    __shared__ float bqx[NBOX], bqy[NBOX], brv[NBOX];
    __shared__ int wcnt[4];
    if (tid < NBOX){
        const float* bp = rois + (size_t)(f*NBOX + tid)*7;
        float bx=bp[0], by=bp[1], dx=bp[3], dy=bp[4];
        float hx=__fmul_rn(dx,0.5f), hy=__fmul_rn(dy,0.5f);
        float hd=sqrtf(__fadd_rn(__fmul_rn(hx,hx),__fmul_rn(hy,hy)));
        brv[tid]=ceilf(__fdiv_rn(__fmul_rn(hd,1.1f),0.4f));
        bqx[tid]=floorf(__fdiv_rn(__fsub_rn(bx,-75.2f),0.4f));
        bqy[tid]=floorf(__fdiv_rn(__fsub_rn(by,-75.2f),0.4f));
    }
    flags[f*NPTS+n] = 0;
    __syncthreads();
    const float* pp = pts + (size_t)(f*NPTS+n)*5;
    float x=pp[0], y=pp[1], z=pp[2], it=pp[3], ts=pp[4];
    float cx=floorf(__fdiv_rn(__fsub_rn(x,-75.2f),0.4f));
    float cy=floorf(__fdiv_rn(__fsub_rn(y,-75.2f),0.4f));
    bool pred=false;
    for (int m=0;m<NBOX;m++)
        if (fabsf(bqx[m]-cx)<brv[m] && fabsf(bqy[m]-cy)<brv[m]){ pred=true; break; }
    spk[f*NPTS+n]=make_float4(x,y,z,pred?1.f:0.f);
    epk[f*NPTS+n]=make_float2(it,ts);
    uint64_t m = __ballot(pred);
    if (lane == 0) wcnt[wv] = __popcll(m);
    __syncthreads();
    if (tid == 0) ccnt[f*16+chunk] = wcnt[0]+wcnt[1]+wcnt[2]+wcnt[3];
}

/* -- K1b: parallel order-preserving compaction (1 block per 256-chunk) --- */
__global__ void k_valid(const float4* __restrict__ spk, const float2* __restrict__ epk,
                        const int* __restrict__ ccnt,
                        float4* __restrict__ vpk, float2* __restrict__ vek,
                        int* __restrict__ vorig, int* __restrict__ vcnt)
{
    int f = blockIdx.x >> 4;
    int chunk = blockIdx.x & 15;
    int tid = threadIdx.x, wv = tid >> 6, lane = tid & 63;
    __shared__ int wcnt[4];
    int base = 0;
    for (int i=0;i<chunk;i++) base += ccnt[f*16+i];
    int j = (chunk << 8) | tid;
    float4 q = spk[f*NPTS+j];
    float2 e = epk[f*NPTS+j];
    bool pred = q.w > 0.5f;
    uint64_t m = __ballot(pred);
    uint64_t below = (1ull<<lane)-1ull;
    int lp = __popcll(m & below);
    if (lane == 0) wcnt[wv] = __popcll(m);
    __syncthreads();
    int off = base;
    for (int w=0; w<wv; w++) off += wcnt[w];
    if (pred){
        int pos = off + lp;
        float sb = __fadd_rn(__fadd_rn(__fmul_rn(q.x,q.x),__fmul_rn(q.y,q.y)),__fmul_rn(q.z,q.z));
        vpk[f*NPTS+pos] = make_float4(q.x,q.y,q.z,sb);
        vek[f*NPTS+pos] = e;
        vorig[f*NPTS+pos] = j;
    }
    if (chunk == 15 && tid == 0){
        int t = base + wcnt[0]+wcnt[1]+wcnt[2]+wcnt[3];
        vcnt[f] = t;
    }
}

/* ------ K2: per-box stable top-k -> out0, sidx; fused dedupe-append ----- */
__global__ void k_select(const float4* __restrict__ spk, const float2* __restrict__ epk,
                         const float4* __restrict__ vpk, const int* __restrict__ vorig,
                         const int* __restrict__ vcnt,
                         const float* __restrict__ rois, float* __restrict__ out,
                         int* __restrict__ sidx, int* __restrict__ flags,
                         int* __restrict__ gcnt, int* __restrict__ glist)
{
    int id = blockIdx.x;           /* 0..1023 : (f, m) */
    int f = id >> 7, m = id & 127;
    int lane = threadIdx.x;
    const float* bp = rois + (size_t)(f*NBOX+m)*7;
    float bx=bp[0], by=bp[1], dx=bp[3], dy=bp[4];
    float hx=__fmul_rn(dx,0.5f), hy=__fmul_rn(dy,0.5f);
    float hd=sqrtf(__fadd_rn(__fmul_rn(hx,hx),__fmul_rn(hy,hy)));
    float rr=__fmul_rn(hd,1.1f);

    __shared__ int lt[32], lf[32];
    const float4* fsp = spk + f*NPTS;
    const float4* fvp = vpk + f*NPTS;
    const int*    fvo = vorig + f*NPTS;
    int vc = vcnt[f];
    uint64_t below = (1ull<<lane)-1ull;

    /* phase A: masked candidates from valid list, 2-deep pipelined */
    int cT=0;
    for (int v0=0; v0<vc; v0+=128){
        int viA = v0 + lane;
        int viB = v0 + 64 + lane;
        int vicA = min(viA, vc-1);
        int vicB = min(viB, vc-1);
        float4 qA = fvp[vicA];
        float4 qB = fvp[vicB];
        {
            float ddx=__fsub_rn(bx,qA.x), ddy=__fsub_rn(by,qA.y);
            float dis=sqrtf(__fadd_rn(__fmul_rn(ddx,ddx),__fmul_rn(ddy,ddy)));
            bool pm = (viA < vc) && (dis <= rr);
            uint64_t mT=__ballot(pm);
            if (pm){ int pos=cT+__popcll(mT&below); if (pos<32) lt[pos]=fvo[vicA]; }
            cT += __popcll(mT);
            if (cT>=32) break;
        }
        if (v0 + 64 < vc){
            float ddx=__fsub_rn(bx,qB.x), ddy=__fsub_rn(by,qB.y);
            float dis=sqrtf(__fadd_rn(__fmul_rn(ddx,ddx),__fmul_rn(ddy,ddy)));
            bool pm = (viB < vc) && (dis <= rr);
            uint64_t mT=__ballot(pm);
            if (pm){ int pos=cT+__popcll(mT&below); if (pos<32) lt[pos]=fvo[vicB]; }
            cT += __popcll(mT);
            if (cT>=32) break;
        }
    }
    /* phase B: fillers = first 32 original indices failing the mask */
    int cF=0;
    for (int j0=0; j0<NPTS; j0+=64){
        int j=j0+lane;
        float4 q = fsp[j];
        float ddx=__fsub_rn(bx,q.x), ddy=__fsub_rn(by,q.y);
        float dis=sqrtf(__fadd_rn(__fmul_rn(ddx,ddx),__fmul_rn(ddy,ddy)));
        bool fl = !((dis <= rr) && (q.w > 0.5f));
        uint64_t mF=__ballot(fl);
        if (fl){ int pos=cF+__popcll(mF&below); if (pos<32) lf[pos]=j; }
        cF += __popcll(mF);
        if (cF>=32) break;
    }
    __syncthreads();
    cT = min(cT,32);
    if (lane < 32){
        int s = lane;
        bool masked = s < cT;
        int idx = masked ? lt[s] : lf[s-cT];
        float mk = masked ? 1.f : 0.f;
        sidx[(f*NBOX+m)*NS+s]=idx;
        int b = f >> 2, t = f & 3;
        size_t row = (((size_t)(b*NBOX+m))*TT + t)*NS + s;
        float4 q = fsp[idx]; float2 e = epk[f*NPTS+idx];
        float* o0 = out + row*5;
        o0[0]=q.x*mk; o0[1]=q.y*mk; o0[2]=q.z*mk; o0[3]=e.x*mk; o0[4]=e.y*mk;
        /* fused dedupe-append to global needlist */
        int old = atomicExch(&flags[f*NPTS+idx], 1);
        bool fresh = (old == 0);
        uint64_t mm = __ballot(fresh);
        if (fresh){
            int ldr = __ffsll((unsigned long long)mm) - 1;
            int base = 0;
            if (lane == ldr) base = atomicAdd(gcnt, __popcll(mm));
            base = __shfl(base, ldr);
            glist[base + __popcll(mm & below)] = (f<<12) | idx;
        }
    }
}

/* -- K4: scan + channel-major MLPs; LDS float4 h-bcast; ILP-8 batches ---- */
__global__ __launch_bounds__(256) void k_mlp(
    const float4* __restrict__ spk, const float2* __restrict__ epk,
    const float4* __restrict__ vpk, const float2* __restrict__ vek,
    const int* __restrict__ vcnt,
    const int* __restrict__ gcntp, const int* __restrict__ glist,
    float* __restrict__ feats, const float* __restrict__ wt,
    const float* __restrict__ b00,const float* __restrict__ b01,
    const float* __restrict__ b02,const float* __restrict__ b10,
    const float* __restrict__ b11,const float* __restrict__ b12)
{
    int gcnt = *gcntp;
    if ((int)blockIdx.x * 4 >= gcnt) return;
    int tid = threadIdx.x;
    int wv = tid >> 6, lane = tid & 63;
    __shared__ int lists[4][48];
    __shared__ float h1buf[4][8][36];
    __shared__ float h2buf[4][8][36];
    int* l1 = lists[wv];
    int* l2 = lists[wv]+16;
    float (*h1b)[36] = h1buf[wv];
    float (*h2b)[36] = h2buf[wv];

    /* ---- per-lane weight rows, loaded COALESCED from transposed copy ---- */
    float wr00[5], wr01[16], wr02[16], wr10[5], wr11[32], wr12[32];
    float br00=0.f, br01=0.f, br02=0.f, br10=0.f, br11=0.f, br12=0.f;
    #pragma unroll
    for (int i=0;i<5;i++){ wr00[i]=0.f; wr10[i]=0.f; }
    #pragma unroll
    for (int i=0;i<16;i++){ wr01[i]=0.f; wr02[i]=0.f; }
    #pragma unroll
    for (int i=0;i<32;i++){ wr11[i]=0.f; wr12[i]=0.f; }
    if (lane < 16){
        #pragma unroll
        for (int i=0;i<5;i++)  wr00[i]=wt[i*16+lane];
        br00=b00[lane];
        #pragma unroll
        for (int i=0;i<16;i++) wr01[i]=wt[80+i*16+lane];
        br01=b01[lane];
    }
    if (lane < 32){
        #pragma unroll
        for (int i=0;i<16;i++) wr02[i]=wt[336+i*32+lane];
        br02=b02[lane];
        #pragma unroll
        for (int i=0;i<5;i++)  wr10[i]=wt[848+i*32+lane];
        br10=b10[lane];
        #pragma unroll
        for (int i=0;i<32;i++) wr11[i]=wt[1008+i*32+lane];
        br11=b11[lane];
    }
    #pragma unroll
    for (int i=0;i<32;i++) wr12[i]=wt[2032+i*64+lane];
    br12=b12[lane];

    const float RR1 = (float)(0.8*0.8);
    const float RR2 = (float)(1.6*1.6);
    uint64_t below = (1ull<<lane)-1ull;

    for (int li = blockIdx.x*4 + wv; li < gcnt; li += 8192){
        int pe = glist[li];
        int f = pe >> 12, n = pe & 4095;
        const float4* fsp = spk + f*NPTS;
        const float2* fep = epk + f*NPTS;
        const float4* fvp = vpk + f*NPTS;
        const float2* fve = vek + f*NPTS;
        int vc = vcnt[f];
        float4 me = fsp[n];
        float sa = __fadd_rn(__fadd_rn(__fmul_rn(me.x,me.x),__fmul_rn(me.y,me.y)),__fmul_rn(me.z,me.z));

        /* ---- neighbor scan over valid list ---- */
        int cnt1=0, cnt2=0;
        for (int v0=0; v0<vc; v0+=64){
            int vi = v0 + lane;
            int vic = min(vi, vc-1);
            float4 q = fvp[vic];
            float dot = __fadd_rn(__fadd_rn(__fmul_rn(me.x,q.x),__fmul_rn(me.y,q.y)),__fmul_rn(me.z,q.z));
            float d2 = fmaxf(__fsub_rn(__fadd_rn(sa,q.w),__fmul_rn(2.0f,dot)), 0.f);
            bool inb = (vi < vc);
            bool p1 = inb && (d2 < RR1);
            bool p2 = inb && (d2 < RR2);
            uint64_t m1 = __ballot(p1), m2 = __ballot(p2);
            if (p1){ int pos = cnt1 + __popcll(m1 & below); if (pos < 16) l1[pos] = vi; }
            if (p2){ int pos = cnt2 + __popcll(m2 & below); if (pos < 32) l2[pos] = vi; }
            cnt1 += __popcll(m1); cnt2 += __popcll(m2);
            if (cnt1 >= 16 && cnt2 >= 32) break;
        }
        cnt1 = min(cnt1,16); cnt2 = min(cnt2,32);

        float* fo = feats + (size_t)(f*NPTS+n)*FEATC;
        float4 q0 = fsp[0]; float2 e0 = fep[0];

        /* ---- MLP0: 16 nbrs, 5->16->16->32, batches of 8, LDS h-bcast ---- */
        {
            float pmax = 0.f;
            #pragma unroll 1
            for (int kb=0; kb<16; kb+=8){
                float4 qb[8]; float2 eb[8];
                #pragma unroll
                for (int j=0;j<8;j++){
                    int kk = kb+j;
                    int vi = (cnt1>0) ? ((kk<cnt1)? l1[kk] : l1[0]) : -1;
                    if (vi >= 0){ qb[j]=fvp[vi]; eb[j]=fve[vi]; }
                    else        { qb[j]=q0;      eb[j]=e0; }
                }
                #pragma unroll
                for (int j=0;j<8;j++){
                    float a1 = br00;
                    a1 += __fsub_rn(qb[j].x,me.x)*wr00[0];
                    a1 += __fsub_rn(qb[j].y,me.y)*wr00[1];
                    a1 += __fsub_rn(qb[j].z,me.z)*wr00[2];
                    a1 += eb[j].x*wr00[3];
                    a1 += eb[j].y*wr00[4];
                    float h = fmaxf(a1,0.f);
                    if (lane < 16) h1b[j][lane] = h;
                }
                float a2[8] = {br01,br01,br01,br01,br01,br01,br01,br01};
                #pragma unroll
                for (int c4=0;c4<4;c4++){
                    float4 hv[8];
                    #pragma unroll
                    for (int j=0;j<8;j++) hv[j] = *(const float4*)&h1b[j][c4*4];
                    #pragma unroll
                    for (int cc=0;cc<4;cc++){
                        float w = wr01[c4*4+cc];
                        #pragma unroll
                        for (int j=0;j<8;j++){
                            float h = (cc==0)?hv[j].x:(cc==1)?hv[j].y:(cc==2)?hv[j].z:hv[j].w;
                            a2[j] += h*w;
                        }
                    }
                }
                #pragma unroll
                for (int j=0;j<8;j++){
                    float h = fmaxf(a2[j],0.f);
                    if (lane < 16) h2b[j][lane] = h;
                }
                float a3[8] = {br02,br02,br02,br02,br02,br02,br02,br02};
                #pragma unroll
                for (int c4=0;c4<4;c4++){
                    float4 hv[8];
                    #pragma unroll
                    for (int j=0;j<8;j++) hv[j] = *(const float4*)&h2b[j][c4*4];
                    #pragma unroll
                    for (int cc=0;cc<4;cc++){
                        float w = wr02[c4*4+cc];
                        #pragma unroll
                        for (int j=0;j<8;j++){
                            float h = (cc==0)?hv[j].x:(cc==1)?hv[j].y:(cc==2)?hv[j].z:hv[j].w;
                            a3[j] += h*w;
                        }
                    }
                }
                #pragma unroll
                for (int j=0;j<8;j++) pmax = fmaxf(pmax, fmaxf(a3[j],0.f));
            }
            if (lane < 3){
                float mv = (lane==0)? me.x : ((lane==1)? me.y : me.z);
                fo[lane] = mv;
            }
            if (lane < 32) fo[3+lane] = pmax;
        }

        /* ---- MLP1: 32 nbrs, 5->32->32->64, batches of 8, LDS h-bcast ---- */
        {
            float pmax = 0.f;
            #pragma unroll 1
            for (int kb=0; kb<32; kb+=8){
                float4 qb[8]; float2 eb[8];
                #pragma unroll
                for (int j=0;j<8;j++){
                    int kk = kb+j;
                    int vi = (cnt2>0) ? ((kk<cnt2)? l2[kk] : l2[0]) : -1;
                    if (vi >= 0){ qb[j]=fvp[vi]; eb[j]=fve[vi]; }
                    else        { qb[j]=q0;      eb[j]=e0; }
                }
                #pragma unroll
                for (int j=0;j<8;j++){
                    float a1 = br10;
                    a1 += __fsub_rn(qb[j].x,me.x)*wr10[0];
                    a1 += __fsub_rn(qb[j].y,me.y)*wr10[1];
                    a1 += __fsub_rn(qb[j].z,me.z)*wr10[2];
                    a1 += eb[j].x*wr10[3];
                    a1 += eb[j].y*wr10[4];
                    float h = fmaxf(a1,0.f);
                    if (lane < 32) h1b[j][lane] = h;
                }
                float a2[8] = {br11,br11,br11,br11,br11,br11,br11,br11};
                #pragma unroll
                for (int c4=0;c4<8;c4++){
                    float4 hv[8];
                    #pragma unroll
                    for (int j=0;j<8;j++) hv[j] = *(const float4*)&h1b[j][c4*4];
                    #pragma unroll
                    for (int cc=0;cc<4;cc++){
                        float w = wr11[c4*4+cc];
                        #pragma unroll
                        for (int j=0;j<8;j++){
                            float h = (cc==0)?hv[j].x:(cc==1)?hv[j].y:(cc==2)?hv[j].z:hv[j].w;
                            a2[j] += h*w;
                        }
                    }
                }
                #pragma unroll
                for (int j=0;j<8;j++){
                    float h = fmaxf(a2[j],0.f);
                    if (lane < 32) h2b[j][lane] = h;
                }
                float a3[8] = {br12,br12,br12,br12,br12,br12,br12,br12};
                #pragma unroll
                for (int c4=0;c4<8;c4++){
                    float4 hv[8];
                    #pragma unroll
                    for (int j=0;j<8;j++) hv[j] = *(const float4*)&h2b[j][c4*4];
                    #pragma unroll
                    for (int cc=0;cc<4;cc++){
                        float w = wr12[c4*4+cc];
                        #pragma unroll
                        for (int j=0;j<8;j++){
                            float h = (cc==0)?hv[j].x:(cc==1)?hv[j].y:(cc==2)?hv[j].z:hv[j].w;
                            a3[j] += h*w;
                        }
                    }
                }
                #pragma unroll
                for (int j=0;j<8;j++) pmax = fmaxf(pmax, fmaxf(a3[j],0.f));
            }
            fo[35+lane] = pmax;
        }
    }
}

/* ---------------- K5: gather feats rows -> out1 ------------------------- */
__global__ void k_gather(const float* __restrict__ feats, const int* __restrict__ sidx,
                         float* __restrict__ out)
{
    int id = blockIdx.x;           /* 0..1023 : (f, m) */
    int f = id >> 7, m = id & 127;
    int tid = threadIdx.x;
    int s = tid >> 3, j = tid & 7;
    int idx = sidx[(f*NBOX+m)*NS+s];
    int b = f >> 2, t = f & 3;
    size_t row = (((size_t)(b*NBOX+m))*TT + t)*NS + s;
    const float* fi = feats + (size_t)(f*NPTS+idx)*FEATC;
    float* o1 = out + OUT1OFF + row*FEATC;
    for (int c=j; c<FEATC; c+=8) o1[c]=fi[c];
}

extern "C" void kernel_launch(void* const* d_in, const int* in_sizes, int n_in,
                              void* d_out, int out_size, void* d_ws, size_t ws_size,
                              hipStream_t stream)
{
    const float* pts  = (const float*)d_in[0];
    const float* rois = (const float*)d_in[1];
    const float* w00=(const float*)d_in[2],  *b00=(const float*)d_in[3];
    const float* w01=(const float*)d_in[4],  *b01=(const float*)d_in[5];
    const float* w02=(const float*)d_in[6],  *b02=(const float*)d_in[7];
    const float* w10=(const float*)d_in[8],  *b10=(const float*)d_in[9];
    const float* w11=(const float*)d_in[10], *b11=(const float*)d_in[11];
    const float* w12=(const float*)d_in[12], *b12=(const float*)d_in[13];
    float* out = (float*)d_out;

    char* ws = (char*)d_ws;
    float4* spk   = (float4*)(ws + WS_SPK);
    float2* epk   = (float2*)(ws + WS_EPK);
    float*  feats = (float*) (ws + WS_FEATS);
    int*    sidx  = (int*)   (ws + WS_SIDX);
    int*    flags = (int*)   (ws + WS_FLAGS);
    int*    gcnt  = (int*)   (ws + WS_NCNT);
    int*    glist = (int*)   (ws + WS_NLST);
    float4* vpk   = (float4*)(ws + WS_VPK);
    float2* vek   = (float2*)(ws + WS_VEK);
    int*    vorig = (int*)   (ws + WS_VORIG);
    int*    vcnt  = (int*)   (ws + WS_VCNT);
    float*  wtr   = (float*) (ws + WS_WT);
    int*    ccnt  = (int*)   (ws + WS_CCNT);

    hipLaunchKernelGGL(k_prep,   dim3(NFRM*16+1), dim3(256), 0, stream,
                       pts, rois, spk, epk, w00,w01,w02,w10,w11,w12, wtr, flags, gcnt, ccnt);
    hipLaunchKernelGGL(k_valid,  dim3(NFRM*16), dim3(256), 0, stream,
                       spk, epk, ccnt, vpk, vek, vorig, vcnt);
    hipLaunchKernelGGL(k_select, dim3(NFRM*NBOX), dim3(64), 0, stream,
                       spk, epk, vpk, vorig, vcnt, rois, out, sidx, flags, gcnt, glist);
    hipLaunchKernelGGL(k_mlp,    dim3(2048), dim3(256), 0, stream,
                       spk, epk, vpk, vek, vcnt, gcnt, glist, feats, wtr,
                       b00,b01,b02,b10,b11,b12);
    hipLaunchKernelGGL(k_gather, dim3(NFRM*NBOX), dim3(256), 0, stream,
                       feats, sidx, out);
}